// Round 8
// baseline (129.648 us; speedup 1.0000x reference)
//
#include <hip/hip_runtime.h>

#define NT1 512
#define NT2 256

struct WPtrs { const float* W[7]; const float* Bv[7]; };

// K2 state swizzle (unchanged)
__device__ __forceinline__ int scr(int ci) { return ci ^ ((ci >> 4) & 7); }

__device__ __forceinline__ float4 relu4(float4 a) {
  return make_float4(fmaxf(a.x,0.f), fmaxf(a.y,0.f), fmaxf(a.z,0.f), fmaxf(a.w,0.f));
}

__device__ __forceinline__ void fma4(float4& acc, float s, const float4& wv) {
  acc.x = fmaf(s, wv.x, acc.x); acc.y = fmaf(s, wv.y, acc.y);
  acc.z = fmaf(s, wv.z, acc.z); acc.w = fmaf(s, wv.w, acc.w);
}

// ---------------- prep: transpose W1..W7 + biases for coalesced K1 loads ----------
// W'[lvl][s][c][dq][k][4] at float off 128*(K-2); B'[lvl][dq][k][4] at 32512 + 8*(K-2).
__global__ void bfly_prep(WPtrs P, float* __restrict__ wt) {
  int e = blockIdx.x * 256 + threadIdx.x;
  if (e < 32512) {
    int lvl = 1;
    while (lvl < 7 && e >= 128 * ((1 << (lvl + 1)) - 2)) ++lvl;
    int K = 1 << lvl;
    int off = 128 * (K - 2);
    int i = e - off;                       // ((k*2+s)*8+c)*8+d
    int d = i & 7, c = (i >> 3) & 7, s = (i >> 6) & 1, k = i >> 7;
    wt[off + (((s*8 + c)*2 + (d >> 2)) * K + k) * 4 + (d & 3)] = P.W[lvl-1][i];
  } else if (e < 34544) {
    int eb = e - 32512;
    int lvl = 1;
    while (lvl < 7 && eb >= 8 * ((1 << (lvl + 1)) - 2)) ++lvl;
    int K = 1 << lvl;
    int off = 8 * (K - 2);
    int i = eb - off;                      // k*8 + d
    int d = i & 7, k = i >> 3;
    wt[32512 + off + ((d >> 2) * K + k) * 4 + (d & 3)] = P.Bv[lvl-1][i];
  }
}

// K1 level transform. State: plane h at chunk h*1024 + row. Row r = t*K + k.
// Child (k,t) reads parents p0 = 2t*Kp + kp, p1 = p0 + Kp.
// Weights from transposed wt: f4 index = 32*(K-2) + ((s*8+c)*2+th)*K + k
// -> lane-consecutive in k = coalesced.
template<int LVL>
__device__ __forceinline__ void k1_level(const float4* __restrict__ src,
                                         float4* __restrict__ dst,
                                         const float4* __restrict__ wt4,
                                         int g, int th) {
  constexpr int K  = 1 << LVL;
  constexpr int Kp = K >> 1;
  const int k = g & (K - 1);
  const int tIdx = g >> LVL;
  const int kp = k >> 1;
  const float4* wp = wt4 + 32 * (K - 2) + th * K + k;
  float4 wa0 = wp[0],      wa1 = wp[2*K],  wa2 = wp[4*K],  wa3 = wp[6*K];
  float4 wa4 = wp[8*K],    wa5 = wp[10*K], wa6 = wp[12*K], wa7 = wp[14*K];
  float4 wb0 = wp[16*K],   wb1 = wp[18*K], wb2 = wp[20*K], wb3 = wp[22*K];
  float4 wb4 = wp[24*K],   wb5 = wp[26*K], wb6 = wp[28*K], wb7 = wp[30*K];
  const float4 bias = wt4[8128 + 2*(K - 2) + th * K + k];
  __builtin_amdgcn_sched_barrier(0);     // keep weight loads hoisted above the loop
  const int rbase = 2 * tIdx * Kp + kp;
  const int wbase = th * 1024 + tIdx * K + k;
#pragma unroll
  for (int i = 0; i < 4; ++i) {
    float4 A0 = src[rbase + 256*i];
    float4 A1 = src[rbase + 256*i + 1024];
    float4 C0 = src[rbase + 256*i + Kp];
    float4 C1 = src[rbase + 256*i + Kp + 1024];
    float4 a = bias;
    fma4(a, A0.x, wa0); fma4(a, A0.y, wa1); fma4(a, A0.z, wa2); fma4(a, A0.w, wa3);
    fma4(a, A1.x, wa4); fma4(a, A1.y, wa5); fma4(a, A1.z, wa6); fma4(a, A1.w, wa7);
    fma4(a, C0.x, wb0); fma4(a, C0.y, wb1); fma4(a, C0.z, wb2); fma4(a, C0.w, wb3);
    fma4(a, C1.x, wb4); fma4(a, C1.y, wb5); fma4(a, C1.z, wb6); fma4(a, C1.w, wb7);
    dst[wbase + 256*i] = relu4(a);
  }
}

__global__ __launch_bounds__(NT1, 2) void bfly_k1(
    const float* __restrict__ x, const float* __restrict__ F,
    const float* __restrict__ fbias, const float* __restrict__ wt,
    float* __restrict__ st)
{
  __shared__ float4 sA[2048];
  __shared__ float4 sB[2048];
  const int tid = threadIdx.x;
  const int b = blockIdx.x;
  const int th = tid & 1;
  const int g  = tid >> 1;
  const float4* wt4 = (const float4*)wt;

  // phase 1: input conv (kernel=16, stride=16); write plane-major
  {
    const float4* Fp = (const float4*)(F + th * 4);
    float4 f0 = Fp[0],  f1 = Fp[2],  f2 = Fp[4],  f3 = Fp[6];
    float4 f4 = Fp[8],  f5 = Fp[10], f6 = Fp[12], f7 = Fp[14];
    float4 f8 = Fp[16], f9 = Fp[18], f10 = Fp[20], f11 = Fp[22];
    float4 f12 = Fp[24], f13 = Fp[26], f14 = Fp[28], f15 = Fp[30];
    const float4 bias = *(const float4*)(fbias + th * 4);
    const float* xb = x + (size_t)b * 16384;
#pragma unroll
    for (int i = 0; i < 4; ++i) {
      int n = g + i * 256;
      const float4* xr = (const float4*)(xb + n * 16);
      float4 x0 = xr[0], x1 = xr[1], x2 = xr[2], x3 = xr[3];
      float4 a = bias;
      fma4(a, x0.x, f0);  fma4(a, x0.y, f1);  fma4(a, x0.z, f2);  fma4(a, x0.w, f3);
      fma4(a, x1.x, f4);  fma4(a, x1.y, f5);  fma4(a, x1.z, f6);  fma4(a, x1.w, f7);
      fma4(a, x2.x, f8);  fma4(a, x2.y, f9);  fma4(a, x2.z, f10); fma4(a, x2.w, f11);
      fma4(a, x3.x, f12); fma4(a, x3.y, f13); fma4(a, x3.z, f14); fma4(a, x3.w, f15);
      sA[th * 1024 + n] = relu4(a);
    }
  }
  __syncthreads();

  k1_level<1>(sA, sB, wt4, g, th); __syncthreads();
  k1_level<2>(sB, sA, wt4, g, th); __syncthreads();
  k1_level<3>(sA, sB, wt4, g, th); __syncthreads();
  k1_level<4>(sB, sA, wt4, g, th); __syncthreads();
  k1_level<5>(sA, sB, wt4, g, th); __syncthreads();
  k1_level<6>(sB, sA, wt4, g, th); __syncthreads();
  k1_level<7>(sA, sB, wt4, g, th); __syncthreads();

  // level-7 state in sB (plane-major). st[j][b][t][c]: j = r&127, t = r>>7.
#pragma unroll
  for (int it = 0; it < 4; ++it) {
    int o = tid + it * 512;
    int r = o & 1023, h = o >> 10;
    float4 v = sB[o];
    int j = r & 127, t = r >> 7;
    *(float4*)(st + (size_t)j * 65536 + b * 64 + t * 8 + h * 4) = v;
  }
}

// ---------------- K2: levels 8..10 + dense, weight-stationary (unchanged) ----------------
__global__ __launch_bounds__(NT2, 4) void bfly_k2(
    const float* __restrict__ st,
    const float* __restrict__ W8, const float* __restrict__ B8,
    const float* __restrict__ W9, const float* __restrict__ B9,
    const float* __restrict__ W10, const float* __restrict__ B10,
    const float* __restrict__ fea, float* __restrict__ out)
{
  __shared__ float4 sA[512], sB[512];
  __shared__ float swt[2928];
  const int tid = threadIdx.x;
  const int j = blockIdx.x, b0 = blockIdx.y * 32;
  const int th = tid & 1, g = tid >> 1;

  {
    const float4* s4 = (const float4*)(st + (size_t)j*65536 + (size_t)b0*64);
#pragma unroll
    for (int it = 0; it < 2; ++it) {
      int idx = tid + it*256;
      sA[scr(idx)] = s4[idx];
    }
  }
  {
    float4* d = (float4*)swt;
    for (int i = tid; i < 64;  i += NT2) d[i]       = ((const float4*)(W8  + j*256 ))[i];
    for (int i = tid; i < 128; i += NT2) d[64+i]    = ((const float4*)(W9  + j*512 ))[i];
    for (int i = tid; i < 256; i += NT2) d[192+i]   = ((const float4*)(W10 + j*1024))[i];
    if (tid < 4)  d[448+tid] = ((const float4*)(B8  + j*16))[tid];
    if (tid < 8)  d[452+tid] = ((const float4*)(B9  + j*32))[tid];
    if (tid < 16) d[460+tid] = ((const float4*)(B10 + j*64))[tid];
    for (int i = tid; i < 256; i += NT2) d[476+i]   = ((const float4*)(fea + j*1024))[i];
  }
  __syncthreads();

  auto loadW = [&](int woff, int boff, int k_l, float4* w4, float4& bias) {
#pragma unroll
    for (int s = 0; s < 2; ++s)
#pragma unroll
      for (int c = 0; c < 8; ++c)
        w4[s*8+c] = *(const float4*)(swt + woff + k_l*128 + s*64 + c*8 + th*4);
    bias = *(const float4*)(swt + boff + k_l*8 + th*4);
  };
  auto doItem = [&](const float4* S, float4* D, const float4* w4, float4 bias,
                    int k_l, int bl, int t, int KL, int KPL) {
    int p0 = 2*t*KPL + (k_l >> 1), p1 = p0 + KPL;
    int base = bl * 16;
    float4 A0 = S[scr(base + 2*p0)], A1 = S[scr(base + 2*p0 + 1)];
    float4 C0 = S[scr(base + 2*p1)], C1 = S[scr(base + 2*p1 + 1)];
    float4 a = bias;
    fma4(a, A0.x, w4[0]);  fma4(a, A0.y, w4[1]);  fma4(a, A0.z, w4[2]);  fma4(a, A0.w, w4[3]);
    fma4(a, A1.x, w4[4]);  fma4(a, A1.y, w4[5]);  fma4(a, A1.z, w4[6]);  fma4(a, A1.w, w4[7]);
    fma4(a, C0.x, w4[8]);  fma4(a, C0.y, w4[9]);  fma4(a, C0.z, w4[10]); fma4(a, C0.w, w4[11]);
    fma4(a, C1.x, w4[12]); fma4(a, C1.y, w4[13]); fma4(a, C1.z, w4[14]); fma4(a, C1.w, w4[15]);
    int r = t*KL + k_l;
    D[scr(base + 2*r + th)] = relu4(a);
  };

  { // level 8
    int k_l = g & 1, bl = (g >> 1) & 31, t0 = (g >> 6) * 2;
    float4 w4[16], bias; loadW(0, 1792, k_l, w4, bias);
#pragma unroll
    for (int it = 0; it < 2; ++it) doItem(sA, sB, w4, bias, k_l, bl, t0 + it, 2, 1);
  }
  __syncthreads();
  { // level 9
    int k_l = g & 3, bl = g >> 2;
    float4 w4[16], bias; loadW(256, 1808, k_l, w4, bias);
#pragma unroll
    for (int it = 0; it < 2; ++it) doItem(sB, sA, w4, bias, k_l, bl, it, 4, 2);
  }
  __syncthreads();
  { // level 10
    int k_l = g & 7, bo = g >> 3;
    float4 w4[16], bias; loadW(768, 1840, k_l, w4, bias);
#pragma unroll
    for (int it = 0; it < 2; ++it) doItem(sA, sB, w4, bias, k_l, bo + it*16, 0, 8, 4);
  }
  __syncthreads();
  { // dense
    int ch = tid & 7, b_l = tid >> 3;
    float* op = out + ((size_t)(b0 + b_l)) * 16384 + j * 128;
#pragma unroll
    for (int it = 0; it < 4; ++it) {
      int cc = ch + it*8, k = cc >> 2, fq = cc & 3;
      float4 s0 = sB[scr(b_l*16 + k*2)];
      float4 s1 = sB[scr(b_l*16 + k*2 + 1)];
      float sc[8] = {s0.x,s0.y,s0.z,s0.w,s1.x,s1.y,s1.z,s1.w};
      float4 acc = make_float4(0.f, 0.f, 0.f, 0.f);
#pragma unroll
      for (int c = 0; c < 8; ++c) {
        float4 fv = *(const float4*)(swt + 1904 + k*128 + c*16 + fq*4);
        acc.x = fmaf(sc[c], fv.x, acc.x); acc.y = fmaf(sc[c], fv.y, acc.y);
        acc.z = fmaf(sc[c], fv.z, acc.z); acc.w = fmaf(sc[c], fv.w, acc.w);
      }
      *(float4*)(op + k*16 + fq*4) = acc;
    }
  }
}

extern "C" void kernel_launch(void* const* d_in, const int* in_sizes, int n_in,
                              void* d_out, int out_size, void* d_ws, size_t ws_size,
                              hipStream_t stream) {
  const float* x  = (const float*)d_in[0];
  const float* F  = (const float*)d_in[1];
  const float* fb = (const float*)d_in[2];
  WPtrs P;
  for (int l = 0; l < 7; ++l) {
    P.W[l]  = (const float*)d_in[3 + 2 * l];
    P.Bv[l] = (const float*)d_in[4 + 2 * l];
  }
  const float* W8  = (const float*)d_in[17];
  const float* B8  = (const float*)d_in[18];
  const float* W9  = (const float*)d_in[19];
  const float* B9  = (const float*)d_in[20];
  const float* W10 = (const float*)d_in[21];
  const float* B10 = (const float*)d_in[22];
  const float* fea = (const float*)d_in[23];
  float* wt = (float*)d_ws;            // 34544 floats (transposed W1..7 + biases)
  float* st = (float*)d_ws + 65536;    // level-7 state, 33.5 MB
  float* out = (float*)d_out;

  bfly_prep<<<dim3(135), dim3(256), 0, stream>>>(P, wt);
  bfly_k1<<<dim3(1024), dim3(NT1), 0, stream>>>(x, F, fb, wt, st);
  bfly_k2<<<dim3(128, 32), dim3(NT2), 0, stream>>>(st, W8, B8, W9, B9, W10, B10, fea, out);
}

// Round 9
// 114.340 us; speedup vs baseline: 1.1339x; 1.1339x over previous
//
#include <hip/hip_runtime.h>

struct PrepPtrs { const float* W[7]; const float* Bv[7]; const float* F; const float* fb; };

__device__ __forceinline__ int scr(int ci) { return ci ^ ((ci >> 4) & 7); }
// state-chunk swizzle: fold bits 3-4 into bits 0-1 (involution, spreads 32B/512B strides)
__device__ __forceinline__ int cz(int c) { return c ^ ((c >> 3) & 3); }

__device__ __forceinline__ float4 relu4(float4 a) {
  return make_float4(fmaxf(a.x,0.f), fmaxf(a.y,0.f), fmaxf(a.z,0.f), fmaxf(a.w,0.f));
}
__device__ __forceinline__ void fma4(float4& acc, float s, const float4& wv) {
  acc.x = fmaf(s, wv.x, acc.x); acc.y = fmaf(s, wv.y, acc.y);
  acc.z = fmaf(s, wv.z, acc.z); acc.w = fmaf(s, wv.w, acc.w);
}

// ---------------- prep: pack weights into 80-float (k,th) entries ----------------
// Region A (KA, floats 0..4960): 60 level entries (lvl1-4) + 2 conv entries.
// Region B (KB, floats 4960..40800): 448 entries = 8 q x (8 lvl5 + 16 lvl6 + 32 lvl7).
// Entry: [16 x f4 weights (s*8+c)] [f4 bias] (rest pad).
__global__ void bfly_prep(PrepPtrs P, float* __restrict__ wt) {
  int e = blockIdx.x * 256 + threadIdx.x;
  if (e >= 510 * 68) return;
  int ent = e / 68, r = e % 68, dd = r & 3;
  float v; int dst;
  if (ent < 62) {
    dst = ent * 80 + r;
    if (ent < 60) {
      int lvl, base;
      if (ent < 4)       { lvl = 1; base = 0;  }
      else if (ent < 12) { lvl = 2; base = 4;  }
      else if (ent < 28) { lvl = 3; base = 12; }
      else               { lvl = 4; base = 28; }
      int k = (ent - base) >> 1, th = ent & 1;
      if (r < 64) { int s = r >> 5, c = (r >> 2) & 7;
        v = P.W[lvl-1][k*128 + s*64 + c*8 + th*4 + dd]; }
      else v = P.Bv[lvl-1][k*8 + th*4 + dd];
    } else {
      int th = ent - 60;
      if (r < 64) { int f = r >> 2; v = P.F[f*8 + th*4 + dd]; }
      else v = P.fb[th*4 + dd];
    }
  } else {
    int eb = ent - 62;                 // 0..447
    int q = eb / 56, rem = eb % 56;
    int lvl, Kl, base;
    if (rem < 8)       { lvl = 5; Kl = 4;  base = 0;  }
    else if (rem < 24) { lvl = 6; Kl = 8;  base = 8;  }
    else               { lvl = 7; Kl = 16; base = 24; }
    int rr = rem - base, lk = rr >> 1, th = rr & 1;
    int kg = q * Kl + lk;
    if (r < 64) { int s = r >> 5, c = (r >> 2) & 7;
      v = P.W[lvl-1][kg*128 + s*64 + c*8 + th*4 + dd]; }
    else v = P.Bv[lvl-1][kg*8 + th*4 + dd];
    dst = 4960 + eb * 80 + r;
  }
  wt[dst] = v;
}

// ---------------- KA: conv + levels 1..4, SGPR weights, k-major LDS ----------------
// State: plane th at chunk th*1024 + (k*T + t), swizzled by cz(). Parent reads are
// 2 consecutive chunks; writes stride-1.
template<int L>
__device__ __forceinline__ void ka_level(const float4* __restrict__ src,
                                         float4* __restrict__ dst,
                                         const float4* __restrict__ wt4,
                                         int lane, int wq, int th) {
  constexpr int Kc = 1 << L, Tc = 1024 >> L;
  constexpr int entBase = (Kc - 2) * 2;
  constexpr int kIters = (L <= 2) ? 1 : (1 << (L - 2));
  constexpr int tIters = 4 / kIters;
#pragma unroll
  for (int ik = 0; ik < kIters; ++ik) {
    int k;
    if constexpr (L == 1) k = wq & 1;
    else if constexpr (L == 2) k = wq;
    else k = wq + 4 * ik;
    const float4* e4 = wt4 + (entBase + k * 2 + th) * 20;   // uniform -> s_load
    const int kp = k >> 1;
#pragma unroll
    for (int it = 0; it < tIters; ++it) {
      int t;
      if constexpr (L == 1) t = lane + (wq >> 1) * 64 + it * 128;
      else if constexpr (L == 2) t = lane + it * 64;
      else if constexpr (L == 3) t = lane + it * 64;
      else t = lane;
      int pb = kp * (2 * Tc) + 2 * t;
      float4 A0 = src[cz(pb)],        C0 = src[cz(pb + 1)];
      float4 A1 = src[cz(pb + 1024)], C1 = src[cz(pb + 1025)];
      float4 a = e4[16];
      fma4(a, A0.x, e4[0]);  fma4(a, A0.y, e4[1]);  fma4(a, A0.z, e4[2]);  fma4(a, A0.w, e4[3]);
      fma4(a, A1.x, e4[4]);  fma4(a, A1.y, e4[5]);  fma4(a, A1.z, e4[6]);  fma4(a, A1.w, e4[7]);
      fma4(a, C0.x, e4[8]);  fma4(a, C0.y, e4[9]);  fma4(a, C0.z, e4[10]); fma4(a, C0.w, e4[11]);
      fma4(a, C1.x, e4[12]); fma4(a, C1.y, e4[13]); fma4(a, C1.z, e4[14]); fma4(a, C1.w, e4[15]);
      dst[cz(th * 1024 + k * Tc + t)] = relu4(a);
    }
  }
}

__global__ __launch_bounds__(512, 2) void bfly_ka(
    const float* __restrict__ x, const float* __restrict__ wt,
    float* __restrict__ st1)
{
  __shared__ float4 sA[2048], sB[2048];
  const int tid = threadIdx.x, b = blockIdx.x;
  const int lane = tid & 63;
  const int wv = __builtin_amdgcn_readfirstlane(tid >> 6);
  const int th = wv & 1, wq = wv >> 1;
  const float4* wt4 = (const float4*)wt;

  { // conv: rows n, kernel=16 stride=16; SGPR filter entry 60+th
    const float4* e4 = wt4 + (60 + th) * 20;
    const float* xb = x + (size_t)b * 16384;
#pragma unroll
    for (int i = 0; i < 4; ++i) {
      int n = lane + wq * 64 + i * 256;
      const float4* xr = (const float4*)(xb + n * 16);
      float4 x0 = xr[0], x1 = xr[1], x2 = xr[2], x3 = xr[3];
      float4 a = e4[16];
      fma4(a, x0.x, e4[0]);  fma4(a, x0.y, e4[1]);  fma4(a, x0.z, e4[2]);  fma4(a, x0.w, e4[3]);
      fma4(a, x1.x, e4[4]);  fma4(a, x1.y, e4[5]);  fma4(a, x1.z, e4[6]);  fma4(a, x1.w, e4[7]);
      fma4(a, x2.x, e4[8]);  fma4(a, x2.y, e4[9]);  fma4(a, x2.z, e4[10]); fma4(a, x2.w, e4[11]);
      fma4(a, x3.x, e4[12]); fma4(a, x3.y, e4[13]); fma4(a, x3.z, e4[14]); fma4(a, x3.w, e4[15]);
      sA[cz(th * 1024 + n)] = relu4(a);
    }
  }
  __syncthreads();
  ka_level<1>(sA, sB, wt4, lane, wq, th); __syncthreads();
  ka_level<2>(sB, sA, wt4, lane, wq, th); __syncthreads();
  ka_level<3>(sA, sB, wt4, lane, wq, th); __syncthreads();
  ka_level<4>(sB, sA, wt4, lane, wq, th); __syncthreads();

  // write level-4 state: st1[h][k4][b][t4] (f4), LDS chunk = o (stride-1)
  float4* o4 = (float4*)st1;
#pragma unroll
  for (int it = 0; it < 4; ++it) {
    int o = tid + it * 512;
    int t4 = o & 63, k4 = (o >> 6) & 15, h = o >> 10;
    o4[((size_t)(h * 16 + k4) * 1024 + b) * 64 + t4] = sA[cz(o)];
  }
}

// ---------------- KB: levels 5..7, weight-stationary (q, 8-batch tile) ----------------
template<int LV>
__device__ __forceinline__ void kb_level(const float4* __restrict__ src,
                                         float4* __restrict__ dst,
                                         const float4* __restrict__ wb4,
                                         int lane, int wv) {
  constexpr int Kc = 1 << (LV - 3);     // 4, 8, 16 (local children)
  constexpr int Tc = 128 / Kc;          // 32, 16, 8
  constexpr int Tp = 256 / Kc;          // parent T: 64, 32, 16
  constexpr int entB = (LV == 5) ? 0 : (LV == 6) ? 8 : 24;
  constexpr int kIters = Kc / 4;        // 1, 2, 4
  constexpr int nIt = 4 / kIters;
  const int th = wv & 1, w2 = wv >> 1;
#pragma unroll
  for (int ik = 0; ik < kIters; ++ik) {
    const int lk = w2 + 4 * ik;
    const float4* e4 = wb4 + (entB + lk * 2 + th) * 20;   // uniform -> s_load
    const int lkp = lk >> 1;
#pragma unroll
    for (int it = 0; it < nIt; ++it) {
      int t, bb;
      if constexpr (LV == 5)      { t = lane & 31; bb = (lane >> 5) + it * 2; }
      else if constexpr (LV == 6) { t = lane & 15; bb = (lane >> 4) + it * 4; }
      else                        { t = lane & 7;  bb = lane >> 3; }
      int pb = bb * 256 + lkp * Tp + 2 * t;
      float4 A0 = src[cz(pb)],       C0 = src[cz(pb + 1)];
      float4 A1 = src[cz(pb + 128)], C1 = src[cz(pb + 129)];
      float4 a = e4[16];
      fma4(a, A0.x, e4[0]);  fma4(a, A0.y, e4[1]);  fma4(a, A0.z, e4[2]);  fma4(a, A0.w, e4[3]);
      fma4(a, A1.x, e4[4]);  fma4(a, A1.y, e4[5]);  fma4(a, A1.z, e4[6]);  fma4(a, A1.w, e4[7]);
      fma4(a, C0.x, e4[8]);  fma4(a, C0.y, e4[9]);  fma4(a, C0.z, e4[10]); fma4(a, C0.w, e4[11]);
      fma4(a, C1.x, e4[12]); fma4(a, C1.y, e4[13]); fma4(a, C1.z, e4[14]); fma4(a, C1.w, e4[15]);
      dst[cz(bb * 256 + th * 128 + lk * Tc + t)] = relu4(a);
    }
  }
}

__global__ __launch_bounds__(512, 2) void bfly_kb(
    const float* __restrict__ st1, const float* __restrict__ wt,
    float* __restrict__ st2)
{
  __shared__ float4 s0[2048], s1[2048];
  const int tid = threadIdx.x;
  const int q = blockIdx.x, bt = blockIdx.y;       // q<8, bt<128
  const int lane = tid & 63;
  const int wv = __builtin_amdgcn_readfirstlane(tid >> 6);
  const float4* wb4 = (const float4*)wt + 1240 + q * 56 * 20;   // region B, this q
  const float4* i4 = (const float4*)st1;

  // stage level-4 state: 8 batches x 2 branches x 2 planes x 64 t
#pragma unroll
  for (int it = 0; it < 4; ++it) {
    int o = tid + it * 512;
    int t4 = o & 63, lk4 = (o >> 6) & 1, h = (o >> 7) & 1, bl = o >> 8;
    float4 v = i4[((size_t)(h * 16 + 2 * q + lk4) * 1024 + bt * 8 + bl) * 64 + t4];
    s0[cz(bl * 256 + h * 128 + lk4 * 64 + t4)] = v;
  }
  __syncthreads();
  kb_level<5>(s0, s1, wb4, lane, wv); __syncthreads();
  kb_level<6>(s1, s0, wb4, lane, wv); __syncthreads();
  kb_level<7>(s0, s1, wb4, lane, wv); __syncthreads();

  // write st2[j7][b][t7][h] (same f4 layout KC expects)
  float4* o4 = (float4*)st2;
#pragma unroll
  for (int it = 0; it < 4; ++it) {
    int o = tid + it * 512;
    int h = o & 1, t7 = (o >> 1) & 7, bl = (o >> 4) & 7, lk7 = o >> 7;
    float4 v = s1[cz(bl * 256 + h * 128 + lk7 * 8 + t7)];
    o4[(((size_t)(16 * q + lk7) * 1024 + bt * 8 + bl) * 8 + t7) * 2 + h] = v;
  }
}

// ---------------- KC: levels 8..10 + dense (unchanged from R8) ----------------
__global__ __launch_bounds__(256, 4) void bfly_kc(
    const float* __restrict__ st,
    const float* __restrict__ W8, const float* __restrict__ B8,
    const float* __restrict__ W9, const float* __restrict__ B9,
    const float* __restrict__ W10, const float* __restrict__ B10,
    const float* __restrict__ fea, float* __restrict__ out)
{
  __shared__ float4 sA[512], sB[512];
  __shared__ float swt[2928];
  const int tid = threadIdx.x;
  const int j = blockIdx.x, b0 = blockIdx.y * 32;
  const int th = tid & 1, g = tid >> 1;

  {
    const float4* s4 = (const float4*)(st + (size_t)j*65536 + (size_t)b0*64);
#pragma unroll
    for (int it = 0; it < 2; ++it) {
      int idx = tid + it*256;
      sA[scr(idx)] = s4[idx];
    }
  }
  {
    float4* d = (float4*)swt;
    for (int i = tid; i < 64;  i += 256) d[i]       = ((const float4*)(W8  + j*256 ))[i];
    for (int i = tid; i < 128; i += 256) d[64+i]    = ((const float4*)(W9  + j*512 ))[i];
    for (int i = tid; i < 256; i += 256) d[192+i]   = ((const float4*)(W10 + j*1024))[i];
    if (tid < 4)  d[448+tid] = ((const float4*)(B8  + j*16))[tid];
    if (tid < 8)  d[452+tid] = ((const float4*)(B9  + j*32))[tid];
    if (tid < 16) d[460+tid] = ((const float4*)(B10 + j*64))[tid];
    for (int i = tid; i < 256; i += 256) d[476+i]   = ((const float4*)(fea + j*1024))[i];
  }
  __syncthreads();

  auto loadW = [&](int woff, int boff, int k_l, float4* w4, float4& bias) {
#pragma unroll
    for (int s = 0; s < 2; ++s)
#pragma unroll
      for (int c = 0; c < 8; ++c)
        w4[s*8+c] = *(const float4*)(swt + woff + k_l*128 + s*64 + c*8 + th*4);
    bias = *(const float4*)(swt + boff + k_l*8 + th*4);
  };
  auto doItem = [&](const float4* S, float4* D, const float4* w4, float4 bias,
                    int k_l, int bl, int t, int KL, int KPL) {
    int p0 = 2*t*KPL + (k_l >> 1), p1 = p0 + KPL;
    int base = bl * 16;
    float4 A0 = S[scr(base + 2*p0)], A1 = S[scr(base + 2*p0 + 1)];
    float4 C0 = S[scr(base + 2*p1)], C1 = S[scr(base + 2*p1 + 1)];
    float4 a = bias;
    fma4(a, A0.x, w4[0]);  fma4(a, A0.y, w4[1]);  fma4(a, A0.z, w4[2]);  fma4(a, A0.w, w4[3]);
    fma4(a, A1.x, w4[4]);  fma4(a, A1.y, w4[5]);  fma4(a, A1.z, w4[6]);  fma4(a, A1.w, w4[7]);
    fma4(a, C0.x, w4[8]);  fma4(a, C0.y, w4[9]);  fma4(a, C0.z, w4[10]); fma4(a, C0.w, w4[11]);
    fma4(a, C1.x, w4[12]); fma4(a, C1.y, w4[13]); fma4(a, C1.z, w4[14]); fma4(a, C1.w, w4[15]);
    int r = t*KL + k_l;
    D[scr(base + 2*r + th)] = relu4(a);
  };

  { int k_l = g & 1, bl = (g >> 1) & 31, t0 = (g >> 6) * 2;
    float4 w4[16], bias; loadW(0, 1792, k_l, w4, bias);
#pragma unroll
    for (int it = 0; it < 2; ++it) doItem(sA, sB, w4, bias, k_l, bl, t0 + it, 2, 1);
  }
  __syncthreads();
  { int k_l = g & 3, bl = g >> 2;
    float4 w4[16], bias; loadW(256, 1808, k_l, w4, bias);
#pragma unroll
    for (int it = 0; it < 2; ++it) doItem(sB, sA, w4, bias, k_l, bl, it, 4, 2);
  }
  __syncthreads();
  { int k_l = g & 7, bo = g >> 3;
    float4 w4[16], bias; loadW(768, 1840, k_l, w4, bias);
#pragma unroll
    for (int it = 0; it < 2; ++it) doItem(sA, sB, w4, bias, k_l, bo + it*16, 0, 8, 4);
  }
  __syncthreads();
  { int ch = tid & 7, b_l = tid >> 3;
    float* op = out + ((size_t)(b0 + b_l)) * 16384 + j * 128;
#pragma unroll
    for (int it = 0; it < 4; ++it) {
      int cc = ch + it*8, k = cc >> 2, fq = cc & 3;
      float4 s0v = sB[scr(b_l*16 + k*2)];
      float4 s1v = sB[scr(b_l*16 + k*2 + 1)];
      float sc[8] = {s0v.x,s0v.y,s0v.z,s0v.w,s1v.x,s1v.y,s1v.z,s1v.w};
      float4 acc = make_float4(0.f, 0.f, 0.f, 0.f);
#pragma unroll
      for (int c = 0; c < 8; ++c) {
        float4 fv = *(const float4*)(swt + 1904 + k*128 + c*16 + fq*4);
        acc.x = fmaf(sc[c], fv.x, acc.x); acc.y = fmaf(sc[c], fv.y, acc.y);
        acc.z = fmaf(sc[c], fv.z, acc.z); acc.w = fmaf(sc[c], fv.w, acc.w);
      }
      *(float4*)(op + k*16 + fq*4) = acc;
    }
  }
}

extern "C" void kernel_launch(void* const* d_in, const int* in_sizes, int n_in,
                              void* d_out, int out_size, void* d_ws, size_t ws_size,
                              hipStream_t stream) {
  const float* x  = (const float*)d_in[0];
  PrepPtrs P;
  P.F  = (const float*)d_in[1];
  P.fb = (const float*)d_in[2];
  for (int l = 0; l < 7; ++l) {
    P.W[l]  = (const float*)d_in[3 + 2 * l];
    P.Bv[l] = (const float*)d_in[4 + 2 * l];
  }
  const float* W8  = (const float*)d_in[17];
  const float* B8  = (const float*)d_in[18];
  const float* W9  = (const float*)d_in[19];
  const float* B9  = (const float*)d_in[20];
  const float* W10 = (const float*)d_in[21];
  const float* B10 = (const float*)d_in[22];
  const float* fea = (const float*)d_in[23];
  float* wt  = (float*)d_ws;                 // 40800 floats of packed entries
  float* st2 = (float*)d_ws + 65536;         // 33.5 MB level-7 state
  float* st1 = (float*)d_out;                // 33.5 MB level-4 state (KC overwrites all of d_out)
  float* out = (float*)d_out;

  bfly_prep<<<dim3(136), dim3(256), 0, stream>>>(P, wt);
  bfly_ka<<<dim3(1024), dim3(512), 0, stream>>>(x, wt, st1);
  bfly_kb<<<dim3(8, 128), dim3(512), 0, stream>>>(st1, wt, st2);
  bfly_kc<<<dim3(128, 32), dim3(256), 0, stream>>>(st2, W8, B8, W9, B9, W10, B10, fea, out);
}

// Round 10
// 97.069 us; speedup vs baseline: 1.3356x; 1.1779x over previous
//
#include <hip/hip_runtime.h>

struct PrepPtrs { const float* W[7]; const float* Bv[7]; const float* F; const float* fb; };

// state-chunk swizzle: fold bits 3-4 into bits 0-1 (involution, spreads 32B/512B strides)
__device__ __forceinline__ int cz(int c) { return c ^ ((c >> 3) & 3); }

__device__ __forceinline__ float4 relu4(float4 a) {
  return make_float4(fmaxf(a.x,0.f), fmaxf(a.y,0.f), fmaxf(a.z,0.f), fmaxf(a.w,0.f));
}
__device__ __forceinline__ void fma4(float4& acc, float s, const float4& wv) {
  acc.x = fmaf(s, wv.x, acc.x); acc.y = fmaf(s, wv.y, acc.y);
  acc.z = fmaf(s, wv.z, acc.z); acc.w = fmaf(s, wv.w, acc.w);
}

// ---------------- prep: pack weights into 80-float (k,th) entries (unchanged) ----------
__global__ void bfly_prep(PrepPtrs P, float* __restrict__ wt) {
  int e = blockIdx.x * 256 + threadIdx.x;
  if (e >= 510 * 68) return;
  int ent = e / 68, r = e % 68, dd = r & 3;
  float v; int dst;
  if (ent < 62) {
    dst = ent * 80 + r;
    if (ent < 60) {
      int lvl, base;
      if (ent < 4)       { lvl = 1; base = 0;  }
      else if (ent < 12) { lvl = 2; base = 4;  }
      else if (ent < 28) { lvl = 3; base = 12; }
      else               { lvl = 4; base = 28; }
      int k = (ent - base) >> 1, th = ent & 1;
      if (r < 64) { int s = r >> 5, c = (r >> 2) & 7;
        v = P.W[lvl-1][k*128 + s*64 + c*8 + th*4 + dd]; }
      else v = P.Bv[lvl-1][k*8 + th*4 + dd];
    } else {
      int th = ent - 60;
      if (r < 64) { int f = r >> 2; v = P.F[f*8 + th*4 + dd]; }
      else v = P.fb[th*4 + dd];
    }
  } else {
    int eb = ent - 62;                 // 0..447
    int q = eb / 56, rem = eb % 56;
    int lvl, Kl, base;
    if (rem < 8)       { lvl = 5; Kl = 4;  base = 0;  }
    else if (rem < 24) { lvl = 6; Kl = 8;  base = 8;  }
    else               { lvl = 7; Kl = 16; base = 24; }
    int rr = rem - base, lk = rr >> 1, th = rr & 1;
    int kg = q * Kl + lk;
    if (r < 64) { int s = r >> 5, c = (r >> 2) & 7;
      v = P.W[lvl-1][kg*128 + s*64 + c*8 + th*4 + dd]; }
    else v = P.Bv[lvl-1][kg*8 + th*4 + dd];
    dst = 4960 + eb * 80 + r;
  }
  wt[dst] = v;
}

// ---------------- KA: conv + levels 1..4 (unchanged from R9) ----------------
template<int L>
__device__ __forceinline__ void ka_level(const float4* __restrict__ src,
                                         float4* __restrict__ dst,
                                         const float4* __restrict__ wt4,
                                         int lane, int wq, int th) {
  constexpr int Kc = 1 << L, Tc = 1024 >> L;
  constexpr int entBase = (Kc - 2) * 2;
  constexpr int kIters = (L <= 2) ? 1 : (1 << (L - 2));
  constexpr int tIters = 4 / kIters;
#pragma unroll
  for (int ik = 0; ik < kIters; ++ik) {
    int k;
    if constexpr (L == 1) k = wq & 1;
    else if constexpr (L == 2) k = wq;
    else k = wq + 4 * ik;
    const float4* e4 = wt4 + (entBase + k * 2 + th) * 20;   // uniform -> s_load
    const int kp = k >> 1;
#pragma unroll
    for (int it = 0; it < tIters; ++it) {
      int t;
      if constexpr (L == 1) t = lane + (wq >> 1) * 64 + it * 128;
      else if constexpr (L == 2) t = lane + it * 64;
      else if constexpr (L == 3) t = lane + it * 64;
      else t = lane;
      int pb = kp * (2 * Tc) + 2 * t;
      float4 A0 = src[cz(pb)],        C0 = src[cz(pb + 1)];
      float4 A1 = src[cz(pb + 1024)], C1 = src[cz(pb + 1025)];
      float4 a = e4[16];
      fma4(a, A0.x, e4[0]);  fma4(a, A0.y, e4[1]);  fma4(a, A0.z, e4[2]);  fma4(a, A0.w, e4[3]);
      fma4(a, A1.x, e4[4]);  fma4(a, A1.y, e4[5]);  fma4(a, A1.z, e4[6]);  fma4(a, A1.w, e4[7]);
      fma4(a, C0.x, e4[8]);  fma4(a, C0.y, e4[9]);  fma4(a, C0.z, e4[10]); fma4(a, C0.w, e4[11]);
      fma4(a, C1.x, e4[12]); fma4(a, C1.y, e4[13]); fma4(a, C1.z, e4[14]); fma4(a, C1.w, e4[15]);
      dst[cz(th * 1024 + k * Tc + t)] = relu4(a);
    }
  }
}

__global__ __launch_bounds__(512, 2) void bfly_ka(
    const float* __restrict__ x, const float* __restrict__ wt,
    float* __restrict__ st1)
{
  __shared__ float4 sA[2048], sB[2048];
  const int tid = threadIdx.x, b = blockIdx.x;
  const int lane = tid & 63;
  const int wv = __builtin_amdgcn_readfirstlane(tid >> 6);
  const int th = wv & 1, wq = wv >> 1;
  const float4* wt4 = (const float4*)wt;

  {
    const float4* e4 = wt4 + (60 + th) * 20;
    const float* xb = x + (size_t)b * 16384;
#pragma unroll
    for (int i = 0; i < 4; ++i) {
      int n = lane + wq * 64 + i * 256;
      const float4* xr = (const float4*)(xb + n * 16);
      float4 x0 = xr[0], x1 = xr[1], x2 = xr[2], x3 = xr[3];
      float4 a = e4[16];
      fma4(a, x0.x, e4[0]);  fma4(a, x0.y, e4[1]);  fma4(a, x0.z, e4[2]);  fma4(a, x0.w, e4[3]);
      fma4(a, x1.x, e4[4]);  fma4(a, x1.y, e4[5]);  fma4(a, x1.z, e4[6]);  fma4(a, x1.w, e4[7]);
      fma4(a, x2.x, e4[8]);  fma4(a, x2.y, e4[9]);  fma4(a, x2.z, e4[10]); fma4(a, x2.w, e4[11]);
      fma4(a, x3.x, e4[12]); fma4(a, x3.y, e4[13]); fma4(a, x3.z, e4[14]); fma4(a, x3.w, e4[15]);
      sA[cz(th * 1024 + n)] = relu4(a);
    }
  }
  __syncthreads();
  ka_level<1>(sA, sB, wt4, lane, wq, th); __syncthreads();
  ka_level<2>(sB, sA, wt4, lane, wq, th); __syncthreads();
  ka_level<3>(sA, sB, wt4, lane, wq, th); __syncthreads();
  ka_level<4>(sB, sA, wt4, lane, wq, th); __syncthreads();

  float4* o4 = (float4*)st1;
#pragma unroll
  for (int it = 0; it < 4; ++it) {
    int o = tid + it * 512;
    int t4 = o & 63, k4 = (o >> 6) & 15, h = o >> 10;
    o4[((size_t)(h * 16 + k4) * 1024 + b) * 64 + t4] = sA[cz(o)];
  }
}

// ---------------- KB: levels 5..7 (epilogue layout changed -> st2[j][t][h][b]) ----------------
template<int LV>
__device__ __forceinline__ void kb_level(const float4* __restrict__ src,
                                         float4* __restrict__ dst,
                                         const float4* __restrict__ wb4,
                                         int lane, int wv) {
  constexpr int Kc = 1 << (LV - 3);     // 4, 8, 16 (local children)
  constexpr int Tc = 128 / Kc;
  constexpr int Tp = 256 / Kc;
  constexpr int entB = (LV == 5) ? 0 : (LV == 6) ? 8 : 24;
  constexpr int kIters = Kc / 4;
  constexpr int nIt = 4 / kIters;
  const int th = wv & 1, w2 = wv >> 1;
#pragma unroll
  for (int ik = 0; ik < kIters; ++ik) {
    const int lk = w2 + 4 * ik;
    const float4* e4 = wb4 + (entB + lk * 2 + th) * 20;   // uniform -> s_load
    const int lkp = lk >> 1;
#pragma unroll
    for (int it = 0; it < nIt; ++it) {
      int t, bb;
      if constexpr (LV == 5)      { t = lane & 31; bb = (lane >> 5) + it * 2; }
      else if constexpr (LV == 6) { t = lane & 15; bb = (lane >> 4) + it * 4; }
      else                        { t = lane & 7;  bb = lane >> 3; }
      int pb = bb * 256 + lkp * Tp + 2 * t;
      float4 A0 = src[cz(pb)],       C0 = src[cz(pb + 1)];
      float4 A1 = src[cz(pb + 128)], C1 = src[cz(pb + 129)];
      float4 a = e4[16];
      fma4(a, A0.x, e4[0]);  fma4(a, A0.y, e4[1]);  fma4(a, A0.z, e4[2]);  fma4(a, A0.w, e4[3]);
      fma4(a, A1.x, e4[4]);  fma4(a, A1.y, e4[5]);  fma4(a, A1.z, e4[6]);  fma4(a, A1.w, e4[7]);
      fma4(a, C0.x, e4[8]);  fma4(a, C0.y, e4[9]);  fma4(a, C0.z, e4[10]); fma4(a, C0.w, e4[11]);
      fma4(a, C1.x, e4[12]); fma4(a, C1.y, e4[13]); fma4(a, C1.z, e4[14]); fma4(a, C1.w, e4[15]);
      dst[cz(bb * 256 + th * 128 + lk * Tc + t)] = relu4(a);
    }
  }
}

__global__ __launch_bounds__(512, 2) void bfly_kb(
    const float* __restrict__ st1, const float* __restrict__ wt,
    float* __restrict__ st2)
{
  __shared__ float4 s0[2048], s1[2048];
  const int tid = threadIdx.x;
  const int q = blockIdx.x, bt = blockIdx.y;       // q<8, bt<128
  const int lane = tid & 63;
  const int wv = __builtin_amdgcn_readfirstlane(tid >> 6);
  const float4* wb4 = (const float4*)wt + 1240 + q * 56 * 20;
  const float4* i4 = (const float4*)st1;

#pragma unroll
  for (int it = 0; it < 4; ++it) {
    int o = tid + it * 512;
    int t4 = o & 63, lk4 = (o >> 6) & 1, h = (o >> 7) & 1, bl = o >> 8;
    float4 v = i4[((size_t)(h * 16 + 2 * q + lk4) * 1024 + bt * 8 + bl) * 64 + t4];
    s0[cz(bl * 256 + h * 128 + lk4 * 64 + t4)] = v;
  }
  __syncthreads();
  kb_level<5>(s0, s1, wb4, lane, wv); __syncthreads();
  kb_level<6>(s1, s0, wb4, lane, wv); __syncthreads();
  kb_level<7>(s0, s1, wb4, lane, wv); __syncthreads();

  // write st2[j7][t7][h][b]  (b-minor: KC stages coalesced, stride-1 LDS)
  float4* o4 = (float4*)st2;
#pragma unroll
  for (int it = 0; it < 4; ++it) {
    int o = tid + it * 512;
    int bl = o & 7, t7 = (o >> 3) & 7, h = (o >> 6) & 1, lk7 = o >> 7;
    float4 v = s1[cz(bl * 256 + h * 128 + lk7 * 8 + t7)];
    o4[((size_t)((16 * q + lk7) * 8 + t7) * 2 + h) * 1024 + bt * 8 + bl] = v;
  }
}

// ---------------- KC: levels 8..10 + dense, b-minor LDS (conflict-free) ----------------
// state chunk = h*256 + row*32 + bb  (bb = batch-in-block, lane-minor)
__global__ __launch_bounds__(256, 4) void bfly_kc(
    const float* __restrict__ st,
    const float* __restrict__ W8, const float* __restrict__ B8,
    const float* __restrict__ W9, const float* __restrict__ B9,
    const float* __restrict__ W10, const float* __restrict__ B10,
    const float* __restrict__ fea, float* __restrict__ out)
{
  __shared__ float4 sA[512], sB[512];
  __shared__ float swt[2928];
  const int tid = threadIdx.x;
  const int j = blockIdx.x, b0 = blockIdx.y * 32;
  const int bb = tid & 31, grp = tid >> 5;   // 8 groups

  { // stage state: coalesced global (512B runs), stride-1 LDS
    const float4* s4 = (const float4*)st;
#pragma unroll
    for (int it = 0; it < 2; ++it) {
      int idx = tid + it * 256;
      int t = idx >> 6, h = (idx >> 5) & 1, bl = idx & 31;
      sA[h * 256 + t * 32 + bl] = s4[((size_t)((j * 8 + t) * 2 + h)) * 1024 + b0 + bl];
    }
  }
  { // weights staging (contiguous)
    float4* d = (float4*)swt;
    for (int i = tid; i < 64;  i += 256) d[i]       = ((const float4*)(W8  + j*256 ))[i];
    for (int i = tid; i < 128; i += 256) d[64+i]    = ((const float4*)(W9  + j*512 ))[i];
    for (int i = tid; i < 256; i += 256) d[192+i]   = ((const float4*)(W10 + j*1024))[i];
    if (tid < 4)  d[448+tid] = ((const float4*)(B8  + j*16))[tid];
    if (tid < 8)  d[452+tid] = ((const float4*)(B9  + j*32))[tid];
    if (tid < 16) d[460+tid] = ((const float4*)(B10 + j*64))[tid];
    for (int i = tid; i < 256; i += 256) d[476+i]   = ((const float4*)(fea + j*1024))[i];
  }
  __syncthreads();

  auto loadW = [&](int woff, int boff, int k_l, int th, float4* w4, float4& bias) {
#pragma unroll
    for (int s = 0; s < 2; ++s)
#pragma unroll
      for (int c = 0; c < 8; ++c)
        w4[s*8+c] = *(const float4*)(swt + woff + k_l*128 + s*64 + c*8 + th*4);
    bias = *(const float4*)(swt + boff + k_l*8 + th*4);
  };
  auto mat = [&](const float4& A0, const float4& A1, const float4& C0, const float4& C1,
                 const float4* w4, float4 bias) {
    float4 a = bias;
    fma4(a, A0.x, w4[0]);  fma4(a, A0.y, w4[1]);  fma4(a, A0.z, w4[2]);  fma4(a, A0.w, w4[3]);
    fma4(a, A1.x, w4[4]);  fma4(a, A1.y, w4[5]);  fma4(a, A1.z, w4[6]);  fma4(a, A1.w, w4[7]);
    fma4(a, C0.x, w4[8]);  fma4(a, C0.y, w4[9]);  fma4(a, C0.z, w4[10]); fma4(a, C0.w, w4[11]);
    fma4(a, C1.x, w4[12]); fma4(a, C1.y, w4[13]); fma4(a, C1.z, w4[14]); fma4(a, C1.w, w4[15]);
    return relu4(a);
  };

  { // level 8: sA(v7, rows t=0..7) -> sB (rows 2t+k); grp = (h, k, ti)
    int h = grp >> 2, k = (grp >> 1) & 1, ti = grp & 1;
    float4 w4[16], bias; loadW(0, 1792, k, h, w4, bias);
#pragma unroll
    for (int i = 0; i < 2; ++i) {
      int t = ti + 2 * i;
      float4 A0 = sA[(2*t) * 32 + bb],     A1 = sA[256 + (2*t) * 32 + bb];
      float4 C0 = sA[(2*t+1) * 32 + bb],   C1 = sA[256 + (2*t+1) * 32 + bb];
      sB[h * 256 + (2*t + k) * 32 + bb] = mat(A0, A1, C0, C1, w4, bias);
    }
  }
  __syncthreads();
  { // level 9: sB -> sA ; child (k9,t9): parents p0 = 4t9 + (k9>>1), p1 = p0+2
    int h = grp >> 2, k9 = grp & 3;
    float4 w4[16], bias; loadW(256, 1808, k9, h, w4, bias);
#pragma unroll
    for (int t9 = 0; t9 < 2; ++t9) {
      int p0 = 4 * t9 + (k9 >> 1), p1 = p0 + 2;
      float4 A0 = sB[p0 * 32 + bb], A1 = sB[256 + p0 * 32 + bb];
      float4 C0 = sB[p1 * 32 + bb], C1 = sB[256 + p1 * 32 + bb];
      sA[h * 256 + (t9 * 4 + k9) * 32 + bb] = mat(A0, A1, C0, C1, w4, bias);
    }
  }
  __syncthreads();
  { // level 10: sA -> sB ; k10 = grp; parents p0 = k10>>1, p1 = p0+4 (shared over h)
    int k10 = grp;
    int p0 = k10 >> 1, p1 = p0 + 4;
    float4 A0 = sA[p0 * 32 + bb], A1 = sA[256 + p0 * 32 + bb];
    float4 C0 = sA[p1 * 32 + bb], C1 = sA[256 + p1 * 32 + bb];
#pragma unroll
    for (int h = 0; h < 2; ++h) {
      float4 w4[16], bias; loadW(768, 1840, k10, h, w4, bias);
      sB[h * 256 + k10 * 32 + bb] = mat(A0, A1, C0, C1, w4, bias);
    }
  }
  __syncthreads();
  { // dense: coalesced writes (f-minor lanes); v10 reads are broadcast-grouped
    int ch = tid & 7, b_l = tid >> 3;
    float* op = out + ((size_t)(b0 + b_l)) * 16384 + j * 128;
#pragma unroll
    for (int it = 0; it < 4; ++it) {
      int cc = ch + it*8, k = cc >> 2, fq = cc & 3;
      float4 s0v = sB[k * 32 + b_l];
      float4 s1v = sB[256 + k * 32 + b_l];
      float sc[8] = {s0v.x,s0v.y,s0v.z,s0v.w,s1v.x,s1v.y,s1v.z,s1v.w};
      float4 acc = make_float4(0.f, 0.f, 0.f, 0.f);
#pragma unroll
      for (int c = 0; c < 8; ++c) {
        float4 fv = *(const float4*)(swt + 1904 + k*128 + c*16 + fq*4);
        acc.x = fmaf(sc[c], fv.x, acc.x); acc.y = fmaf(sc[c], fv.y, acc.y);
        acc.z = fmaf(sc[c], fv.z, acc.z); acc.w = fmaf(sc[c], fv.w, acc.w);
      }
      *(float4*)(op + k*16 + fq*4) = acc;
    }
  }
}

extern "C" void kernel_launch(void* const* d_in, const int* in_sizes, int n_in,
                              void* d_out, int out_size, void* d_ws, size_t ws_size,
                              hipStream_t stream) {
  const float* x  = (const float*)d_in[0];
  PrepPtrs P;
  P.F  = (const float*)d_in[1];
  P.fb = (const float*)d_in[2];
  for (int l = 0; l < 7; ++l) {
    P.W[l]  = (const float*)d_in[3 + 2 * l];
    P.Bv[l] = (const float*)d_in[4 + 2 * l];
  }
  const float* W8  = (const float*)d_in[17];
  const float* B8  = (const float*)d_in[18];
  const float* W9  = (const float*)d_in[19];
  const float* B9  = (const float*)d_in[20];
  const float* W10 = (const float*)d_in[21];
  const float* B10 = (const float*)d_in[22];
  const float* fea = (const float*)d_in[23];
  float* wt  = (float*)d_ws;                 // packed KA/KB weight entries
  float* st2 = (float*)d_ws + 65536;         // 33.5 MB level-7 state [j][t][h][b]
  float* st1 = (float*)d_out;                // 33.5 MB level-4 state (KC overwrites d_out)
  float* out = (float*)d_out;

  bfly_prep<<<dim3(136), dim3(256), 0, stream>>>(P, wt);
  bfly_ka<<<dim3(1024), dim3(512), 0, stream>>>(x, wt, st1);
  bfly_kb<<<dim3(8, 128), dim3(512), 0, stream>>>(st1, wt, st2);
  bfly_kc<<<dim3(128, 32), dim3(256), 0, stream>>>(st2, W8, B8, W9, B9, W10, B10, fea, out);
}

// Round 11
// 96.458 us; speedup vs baseline: 1.3441x; 1.0063x over previous
//
#include <hip/hip_runtime.h>

struct PrepPtrs { const float* W[7]; const float* Bv[7]; const float* F; const float* fb; };

// state-chunk swizzle used by KB (unchanged)
__device__ __forceinline__ int cz(int c) { return c ^ ((c >> 3) & 3); }
// KA wave-region pad: +1 chunk per 8 (bijective into [0,288))
__device__ __forceinline__ int pc(int c) { return c + (c >> 3); }

__device__ __forceinline__ float4 relu4(float4 a) {
  return make_float4(fmaxf(a.x,0.f), fmaxf(a.y,0.f), fmaxf(a.z,0.f), fmaxf(a.w,0.f));
}
__device__ __forceinline__ void fma4(float4& acc, float s, const float4& wv) {
  acc.x = fmaf(s, wv.x, acc.x); acc.y = fmaf(s, wv.y, acc.y);
  acc.z = fmaf(s, wv.z, acc.z); acc.w = fmaf(s, wv.w, acc.w);
}

// ---------------- prep: pack weights into 80-float (k,th) entries (unchanged) ----------
__global__ void bfly_prep(PrepPtrs P, float* __restrict__ wt) {
  int e = blockIdx.x * 256 + threadIdx.x;
  if (e >= 510 * 68) return;
  int ent = e / 68, r = e % 68, dd = r & 3;
  float v; int dst;
  if (ent < 62) {
    dst = ent * 80 + r;
    if (ent < 60) {
      int lvl, base;
      if (ent < 4)       { lvl = 1; base = 0;  }
      else if (ent < 12) { lvl = 2; base = 4;  }
      else if (ent < 28) { lvl = 3; base = 12; }
      else               { lvl = 4; base = 28; }
      int k = (ent - base) >> 1, th = ent & 1;
      if (r < 64) { int s = r >> 5, c = (r >> 2) & 7;
        v = P.W[lvl-1][k*128 + s*64 + c*8 + th*4 + dd]; }
      else v = P.Bv[lvl-1][k*8 + th*4 + dd];
    } else {
      int th = ent - 60;
      if (r < 64) { int f = r >> 2; v = P.F[f*8 + th*4 + dd]; }
      else v = P.fb[th*4 + dd];
    }
  } else {
    int eb = ent - 62;                 // 0..447
    int q = eb / 56, rem = eb % 56;
    int lvl, Kl, base;
    if (rem < 8)       { lvl = 5; Kl = 4;  base = 0;  }
    else if (rem < 24) { lvl = 6; Kl = 8;  base = 8;  }
    else               { lvl = 7; Kl = 16; base = 24; }
    int rr = rem - base, lk = rr >> 1, th = rr & 1;
    int kg = q * Kl + lk;
    if (r < 64) { int s = r >> 5, c = (r >> 2) & 7;
      v = P.W[lvl-1][kg*128 + s*64 + c*8 + th*4 + dd]; }
    else v = P.Bv[lvl-1][kg*8 + th*4 + dd];
    dst = 4960 + eb * 80 + r;
  }
  wt[dst] = v;
}

// ---------------- KA: conv + levels 1..4, wave-private subtrees, no level barriers ----
// Wave owns t4-slice of 8 -> constant 128 rows/level. Buffer: [2 planes][128 rows],
// row = k*T + t (k-major), chunk padded by pc(). Ping-pong within wave region.
template<int L>
__device__ __forceinline__ void ka_level(float4* __restrict__ buf,
                                         int srcOff, int dstOff,
                                         const float4* __restrict__ wt4,
                                         int lane) {
  constexpr int K = 1 << L;            // children
  constexpr int T = 128 >> L;          // local t-count (out)
  constexpr int G = 32 >> L;           // t-lanes per (k,th)
  const int kth = lane / G, tg = lane % G;
  const int k = kth >> 1, th = kth & 1;
  const int kp = k >> 1;
  const float4* e4 = wt4 + (((K - 2) * 2 + k * 2 + th) * 20);
  float4 w0 = e4[0],  w1 = e4[1],  w2 = e4[2],  w3 = e4[3];
  float4 w4_ = e4[4], w5 = e4[5],  w6 = e4[6],  w7 = e4[7];
  float4 w8 = e4[8],  w9 = e4[9],  w10 = e4[10], w11 = e4[11];
  float4 w12 = e4[12], w13 = e4[13], w14 = e4[14], w15 = e4[15];
  const float4 bias = e4[16];
#pragma unroll
  for (int it = 0; it < 4; ++it) {
    int t = tg + it * G;
    int pr = kp * (2 * T) + 2 * t;     // parent row (lvl L-1 k-major, T_{L-1}=2T)
    float4 A0 = buf[srcOff + pc(pr)];
    float4 A1 = buf[srcOff + pc(128 + pr)];
    float4 C0 = buf[srcOff + pc(pr + 1)];
    float4 C1 = buf[srcOff + pc(128 + pr + 1)];
    float4 a = bias;
    fma4(a, A0.x, w0);  fma4(a, A0.y, w1);  fma4(a, A0.z, w2);  fma4(a, A0.w, w3);
    fma4(a, A1.x, w4_); fma4(a, A1.y, w5);  fma4(a, A1.z, w6);  fma4(a, A1.w, w7);
    fma4(a, C0.x, w8);  fma4(a, C0.y, w9);  fma4(a, C0.z, w10); fma4(a, C0.w, w11);
    fma4(a, C1.x, w12); fma4(a, C1.y, w13); fma4(a, C1.z, w14); fma4(a, C1.w, w15);
    buf[dstOff + pc(th * 128 + k * T + t)] = relu4(a);
  }
}

__global__ __launch_bounds__(256, 4) void bfly_ka(
    const float* __restrict__ x, const float* __restrict__ wt,
    float* __restrict__ st1)
{
  __shared__ float4 lds[4 * 2 * 288];          // [wave][pp][288]
  const int tid = threadIdx.x;
  const int b = blockIdx.x >> 1, hb = blockIdx.x & 1;
  const int lane = tid & 63;
  const int wv = tid >> 6;                     // 4 waves, t4-slice of 8 each
  const float4* wt4 = (const float4*)wt;
  float4* buf = lds + wv * 576;                // wave-private 2x288

  { // conv: 128 rows/wave; lane = th*32 + ng; writes plane th rows stride-1
    const int th = lane >> 5, ng = lane & 31;
    const float4* e4 = wt4 + (60 + th) * 20;
    float4 f0 = e4[0],  f1 = e4[1],  f2 = e4[2],  f3 = e4[3];
    float4 f4_ = e4[4], f5 = e4[5],  f6 = e4[6],  f7 = e4[7];
    float4 f8 = e4[8],  f9 = e4[9],  f10 = e4[10], f11 = e4[11];
    float4 f12 = e4[12], f13 = e4[13], f14 = e4[14], f15 = e4[15];
    const float4 bias = e4[16];
    const float* xb = x + (size_t)b * 16384 + (hb * 512 + wv * 128) * 16;
#pragma unroll
    for (int i = 0; i < 4; ++i) {
      int n = ng + i * 32;                     // local row
      const float4* xr = (const float4*)(xb + n * 16);
      float4 x0 = xr[0], x1 = xr[1], x2 = xr[2], x3 = xr[3];
      float4 a = bias;
      fma4(a, x0.x, f0);  fma4(a, x0.y, f1);  fma4(a, x0.z, f2);  fma4(a, x0.w, f3);
      fma4(a, x1.x, f4_); fma4(a, x1.y, f5);  fma4(a, x1.z, f6);  fma4(a, x1.w, f7);
      fma4(a, x2.x, f8);  fma4(a, x2.y, f9);  fma4(a, x2.z, f10); fma4(a, x2.w, f11);
      fma4(a, x3.x, f12); fma4(a, x3.y, f13); fma4(a, x3.z, f14); fma4(a, x3.w, f15);
      buf[pc(th * 128 + n)] = relu4(a);
    }
  }
  // levels 1..4 wave-private: buf0 -> buf1 -> buf0 -> buf1 -> buf0
  ka_level<1>(buf, 0, 288, wt4, lane);
  ka_level<2>(buf, 288, 0, wt4, lane);
  ka_level<3>(buf, 0, 288, wt4, lane);
  ka_level<4>(buf, 288, 0, wt4, lane);
  __syncthreads();                             // only barrier: cross-wave epilogue

  // final state per wave in buf0: row = k4*8 + t4l, plane h.
  // st1[h][k4][b][t4g], t4g = hb*32 + t4b; coalesced 512B runs.
  float4* o4 = (float4*)st1;
#pragma unroll
  for (int it = 0; it < 4; ++it) {
    int idx = tid + it * 256;                  // [0,1024)
    int t4b = idx & 31, k4 = (idx >> 5) & 15, h = idx >> 9;
    float4 v = lds[(t4b >> 3) * 576 + pc(h * 128 + k4 * 8 + (t4b & 7))];
    o4[((size_t)(h * 16 + k4) * 1024 + b) * 64 + hb * 32 + t4b] = v;
  }
}

// ---------------- KB: levels 5..7 (unchanged from R10) ----------------
template<int LV>
__device__ __forceinline__ void kb_level(const float4* __restrict__ src,
                                         float4* __restrict__ dst,
                                         const float4* __restrict__ wb4,
                                         int lane, int wv) {
  constexpr int Kc = 1 << (LV - 3);
  constexpr int Tc = 128 / Kc;
  constexpr int Tp = 256 / Kc;
  constexpr int entB = (LV == 5) ? 0 : (LV == 6) ? 8 : 24;
  constexpr int kIters = Kc / 4;
  constexpr int nIt = 4 / kIters;
  const int th = wv & 1, w2 = wv >> 1;
#pragma unroll
  for (int ik = 0; ik < kIters; ++ik) {
    const int lk = w2 + 4 * ik;
    const float4* e4 = wb4 + (entB + lk * 2 + th) * 20;   // uniform -> s_load
    const int lkp = lk >> 1;
#pragma unroll
    for (int it = 0; it < nIt; ++it) {
      int t, bb;
      if constexpr (LV == 5)      { t = lane & 31; bb = (lane >> 5) + it * 2; }
      else if constexpr (LV == 6) { t = lane & 15; bb = (lane >> 4) + it * 4; }
      else                        { t = lane & 7;  bb = lane >> 3; }
      int pb = bb * 256 + lkp * Tp + 2 * t;
      float4 A0 = src[cz(pb)],       C0 = src[cz(pb + 1)];
      float4 A1 = src[cz(pb + 128)], C1 = src[cz(pb + 129)];
      float4 a = e4[16];
      fma4(a, A0.x, e4[0]);  fma4(a, A0.y, e4[1]);  fma4(a, A0.z, e4[2]);  fma4(a, A0.w, e4[3]);
      fma4(a, A1.x, e4[4]);  fma4(a, A1.y, e4[5]);  fma4(a, A1.z, e4[6]);  fma4(a, A1.w, e4[7]);
      fma4(a, C0.x, e4[8]);  fma4(a, C0.y, e4[9]);  fma4(a, C0.z, e4[10]); fma4(a, C0.w, e4[11]);
      fma4(a, C1.x, e4[12]); fma4(a, C1.y, e4[13]); fma4(a, C1.z, e4[14]); fma4(a, C1.w, e4[15]);
      dst[cz(bb * 256 + th * 128 + lk * Tc + t)] = relu4(a);
    }
  }
}

__global__ __launch_bounds__(512, 2) void bfly_kb(
    const float* __restrict__ st1, const float* __restrict__ wt,
    float* __restrict__ st2)
{
  __shared__ float4 s0[2048], s1[2048];
  const int tid = threadIdx.x;
  const int q = blockIdx.x, bt = blockIdx.y;
  const int lane = tid & 63;
  const int wv = __builtin_amdgcn_readfirstlane(tid >> 6);
  const float4* wb4 = (const float4*)wt + 1240 + q * 56 * 20;
  const float4* i4 = (const float4*)st1;

#pragma unroll
  for (int it = 0; it < 4; ++it) {
    int o = tid + it * 512;
    int t4 = o & 63, lk4 = (o >> 6) & 1, h = (o >> 7) & 1, bl = o >> 8;
    float4 v = i4[((size_t)(h * 16 + 2 * q + lk4) * 1024 + bt * 8 + bl) * 64 + t4];
    s0[cz(bl * 256 + h * 128 + lk4 * 64 + t4)] = v;
  }
  __syncthreads();
  kb_level<5>(s0, s1, wb4, lane, wv); __syncthreads();
  kb_level<6>(s1, s0, wb4, lane, wv); __syncthreads();
  kb_level<7>(s0, s1, wb4, lane, wv); __syncthreads();

  float4* o4 = (float4*)st2;
#pragma unroll
  for (int it = 0; it < 4; ++it) {
    int o = tid + it * 512;
    int bl = o & 7, t7 = (o >> 3) & 7, h = (o >> 6) & 1, lk7 = o >> 7;
    float4 v = s1[cz(bl * 256 + h * 128 + lk7 * 8 + t7)];
    o4[((size_t)((16 * q + lk7) * 8 + t7) * 2 + h) * 1024 + bt * 8 + bl] = v;
  }
}

// ---------------- KC: levels 8..10 + dense, b-minor LDS (unchanged from R10) ----------
__global__ __launch_bounds__(256, 4) void bfly_kc(
    const float* __restrict__ st,
    const float* __restrict__ W8, const float* __restrict__ B8,
    const float* __restrict__ W9, const float* __restrict__ B9,
    const float* __restrict__ W10, const float* __restrict__ B10,
    const float* __restrict__ fea, float* __restrict__ out)
{
  __shared__ float4 sA[512], sB[512];
  __shared__ float swt[2928];
  const int tid = threadIdx.x;
  const int j = blockIdx.x, b0 = blockIdx.y * 32;
  const int bb = tid & 31, grp = tid >> 5;

  {
    const float4* s4 = (const float4*)st;
#pragma unroll
    for (int it = 0; it < 2; ++it) {
      int idx = tid + it * 256;
      int t = idx >> 6, h = (idx >> 5) & 1, bl = idx & 31;
      sA[h * 256 + t * 32 + bl] = s4[((size_t)((j * 8 + t) * 2 + h)) * 1024 + b0 + bl];
    }
  }
  {
    float4* d = (float4*)swt;
    for (int i = tid; i < 64;  i += 256) d[i]       = ((const float4*)(W8  + j*256 ))[i];
    for (int i = tid; i < 128; i += 256) d[64+i]    = ((const float4*)(W9  + j*512 ))[i];
    for (int i = tid; i < 256; i += 256) d[192+i]   = ((const float4*)(W10 + j*1024))[i];
    if (tid < 4)  d[448+tid] = ((const float4*)(B8  + j*16))[tid];
    if (tid < 8)  d[452+tid] = ((const float4*)(B9  + j*32))[tid];
    if (tid < 16) d[460+tid] = ((const float4*)(B10 + j*64))[tid];
    for (int i = tid; i < 256; i += 256) d[476+i]   = ((const float4*)(fea + j*1024))[i];
  }
  __syncthreads();

  auto loadW = [&](int woff, int boff, int k_l, int th, float4* w4, float4& bias) {
#pragma unroll
    for (int s = 0; s < 2; ++s)
#pragma unroll
      for (int c = 0; c < 8; ++c)
        w4[s*8+c] = *(const float4*)(swt + woff + k_l*128 + s*64 + c*8 + th*4);
    bias = *(const float4*)(swt + boff + k_l*8 + th*4);
  };
  auto mat = [&](const float4& A0, const float4& A1, const float4& C0, const float4& C1,
                 const float4* w4, float4 bias) {
    float4 a = bias;
    fma4(a, A0.x, w4[0]);  fma4(a, A0.y, w4[1]);  fma4(a, A0.z, w4[2]);  fma4(a, A0.w, w4[3]);
    fma4(a, A1.x, w4[4]);  fma4(a, A1.y, w4[5]);  fma4(a, A1.z, w4[6]);  fma4(a, A1.w, w4[7]);
    fma4(a, C0.x, w4[8]);  fma4(a, C0.y, w4[9]);  fma4(a, C0.z, w4[10]); fma4(a, C0.w, w4[11]);
    fma4(a, C1.x, w4[12]); fma4(a, C1.y, w4[13]); fma4(a, C1.z, w4[14]); fma4(a, C1.w, w4[15]);
    return relu4(a);
  };

  { int h = grp >> 2, k = (grp >> 1) & 1, ti = grp & 1;
    float4 w4[16], bias; loadW(0, 1792, k, h, w4, bias);
#pragma unroll
    for (int i = 0; i < 2; ++i) {
      int t = ti + 2 * i;
      float4 A0 = sA[(2*t) * 32 + bb],     A1 = sA[256 + (2*t) * 32 + bb];
      float4 C0 = sA[(2*t+1) * 32 + bb],   C1 = sA[256 + (2*t+1) * 32 + bb];
      sB[h * 256 + (2*t + k) * 32 + bb] = mat(A0, A1, C0, C1, w4, bias);
    }
  }
  __syncthreads();
  { int h = grp >> 2, k9 = grp & 3;
    float4 w4[16], bias; loadW(256, 1808, k9, h, w4, bias);
#pragma unroll
    for (int t9 = 0; t9 < 2; ++t9) {
      int p0 = 4 * t9 + (k9 >> 1), p1 = p0 + 2;
      float4 A0 = sB[p0 * 32 + bb], A1 = sB[256 + p0 * 32 + bb];
      float4 C0 = sB[p1 * 32 + bb], C1 = sB[256 + p1 * 32 + bb];
      sA[h * 256 + (t9 * 4 + k9) * 32 + bb] = mat(A0, A1, C0, C1, w4, bias);
    }
  }
  __syncthreads();
  { int k10 = grp;
    int p0 = k10 >> 1, p1 = p0 + 4;
    float4 A0 = sA[p0 * 32 + bb], A1 = sA[256 + p0 * 32 + bb];
    float4 C0 = sA[p1 * 32 + bb], C1 = sA[256 + p1 * 32 + bb];
#pragma unroll
    for (int h = 0; h < 2; ++h) {
      float4 w4[16], bias; loadW(768, 1840, k10, h, w4, bias);
      sB[h * 256 + k10 * 32 + bb] = mat(A0, A1, C0, C1, w4, bias);
    }
  }
  __syncthreads();
  { int ch = tid & 7, b_l = tid >> 3;
    float* op = out + ((size_t)(b0 + b_l)) * 16384 + j * 128;
#pragma unroll
    for (int it = 0; it < 4; ++it) {
      int cc = ch + it*8, k = cc >> 2, fq = cc & 3;
      float4 s0v = sB[k * 32 + b_l];
      float4 s1v = sB[256 + k * 32 + b_l];
      float sc[8] = {s0v.x,s0v.y,s0v.z,s0v.w,s1v.x,s1v.y,s1v.z,s1v.w};
      float4 acc = make_float4(0.f, 0.f, 0.f, 0.f);
#pragma unroll
      for (int c = 0; c < 8; ++c) {
        float4 fv = *(const float4*)(swt + 1904 + k*128 + c*16 + fq*4);
        acc.x = fmaf(sc[c], fv.x, acc.x); acc.y = fmaf(sc[c], fv.y, acc.y);
        acc.z = fmaf(sc[c], fv.z, acc.z); acc.w = fmaf(sc[c], fv.w, acc.w);
      }
      *(float4*)(op + k*16 + fq*4) = acc;
    }
  }
}

extern "C" void kernel_launch(void* const* d_in, const int* in_sizes, int n_in,
                              void* d_out, int out_size, void* d_ws, size_t ws_size,
                              hipStream_t stream) {
  const float* x  = (const float*)d_in[0];
  PrepPtrs P;
  P.F  = (const float*)d_in[1];
  P.fb = (const float*)d_in[2];
  for (int l = 0; l < 7; ++l) {
    P.W[l]  = (const float*)d_in[3 + 2 * l];
    P.Bv[l] = (const float*)d_in[4 + 2 * l];
  }
  const float* W8  = (const float*)d_in[17];
  const float* B8  = (const float*)d_in[18];
  const float* W9  = (const float*)d_in[19];
  const float* B9  = (const float*)d_in[20];
  const float* W10 = (const float*)d_in[21];
  const float* B10 = (const float*)d_in[22];
  const float* fea = (const float*)d_in[23];
  float* wt  = (float*)d_ws;                 // packed KA/KB weight entries
  float* st2 = (float*)d_ws + 65536;         // 33.5 MB level-7 state [j][t][h][b]
  float* st1 = (float*)d_out;                // 33.5 MB level-4 state (KC overwrites d_out)
  float* out = (float*)d_out;

  bfly_prep<<<dim3(136), dim3(256), 0, stream>>>(P, wt);
  bfly_ka<<<dim3(2048), dim3(256), 0, stream>>>(x, wt, st1);
  bfly_kb<<<dim3(8, 128), dim3(512), 0, stream>>>(st1, wt, st2);
  bfly_kc<<<dim3(128, 32), dim3(256), 0, stream>>>(st2, W8, B8, W9, B9, W10, B10, fea, out);
}